// Round 4
// baseline (68365.057 us; speedup 1.0000x reference)
//
#include <hip/hip_runtime.h>
#include <math.h>

#define DIMX 512
#define NHEADS 8
#define DHE 64
#define NB 266
#define FFD 2048
#define OUTD 32
#define BATCH 4
#define SEQ 8192
#define NTOK 32768
#define HALF 16384
#define NLAYER 6
#define HCH 64  // chunks per head for ctx/o grids (per half)

#define DN_F 0.35355339059327373f
#define EPS_F 1e-4f

typedef unsigned short ushort_t;
typedef __attribute__((ext_vector_type(8))) short short8;
typedef __attribute__((ext_vector_type(4))) float floatx4;

__device__ __forceinline__ float gelu_f(float x) {
    float x3 = x * x * x;
    return 0.5f * x * (1.0f + tanhf(0.7978845608028654f * (x + 0.044715f * x3)));
}

__device__ __forceinline__ ushort_t f2bf(float f) {
    unsigned int u = __float_as_uint(f);
    unsigned int r = (u + 0x7fffu + ((u >> 16) & 1u)) >> 16;
    return (ushort_t)r;
}
__device__ __forceinline__ float bfu(ushort_t u) { return __uint_as_float(((unsigned int)u) << 16); }
__device__ __forceinline__ float bflo(unsigned int u) { return __uint_as_float(u << 16); }
__device__ __forceinline__ float bfhi(unsigned int u) { return __uint_as_float(u & 0xffff0000u); }

__device__ __forceinline__ unsigned int fkey(float f) {
    unsigned int u = __float_as_uint(f);
    return (u & 0x80000000u) ? ~u : (u | 0x80000000u);
}
__device__ __forceinline__ float funkey(unsigned int k) {
    unsigned int u = (k & 0x80000000u) ? (k & 0x7fffffffu) : ~k;
    return __uint_as_float(u);
}

// dot of one bf16 row (64 elems) against fp32 proj row held in pr[16] (float4)
__device__ __forceinline__ float dot64bf(const ushort_t* kr, const float4* pr) {
    const uint4* k4 = (const uint4*)kr;
    float acc = 0.f;
#pragma unroll
    for (int j = 0; j < 8; j++) {
        uint4 u = k4[j];
        float4 p0 = pr[2 * j], p1 = pr[2 * j + 1];
        acc += bflo(u.x) * p0.x; acc += bfhi(u.x) * p0.y;
        acc += bflo(u.y) * p0.z; acc += bfhi(u.y) * p0.w;
        acc += bflo(u.z) * p1.x; acc += bfhi(u.z) * p1.y;
        acc += bflo(u.w) * p1.z; acc += bfhi(u.w) * p1.w;
    }
    return acc;
}

__global__ __launch_bounds__(256) void zero_kernel(float* __restrict__ p, int n) {
    int i = blockIdx.x * 256 + threadIdx.x;
    if (i < n) p[i] = 0.f;
}

// ---------------- LayerNorm -> bf16 out: one wave per 512-float row ----------------
__global__ __launch_bounds__(256) void ln_bf16_kernel(const float* __restrict__ x,
                                                      const float* __restrict__ g,
                                                      const float* __restrict__ b,
                                                      ushort_t* __restrict__ out) {
    int row = blockIdx.x * 4 + (threadIdx.x >> 6);
    int lane = threadIdx.x & 63;
    const float4* xr = (const float4*)(x + (size_t)row * DIMX);
    float4 v0 = xr[lane];
    float4 v1 = xr[lane + 64];
    float sum = v0.x + v0.y + v0.z + v0.w + v1.x + v1.y + v1.z + v1.w;
#pragma unroll
    for (int off = 32; off; off >>= 1) sum += __shfl_xor(sum, off);
    float mu = sum * (1.0f / 512.0f);
    float var = (v0.x - mu) * (v0.x - mu) + (v0.y - mu) * (v0.y - mu) +
                (v0.z - mu) * (v0.z - mu) + (v0.w - mu) * (v0.w - mu) +
                (v1.x - mu) * (v1.x - mu) + (v1.y - mu) * (v1.y - mu) +
                (v1.z - mu) * (v1.z - mu) + (v1.w - mu) * (v1.w - mu);
#pragma unroll
    for (int off = 32; off; off >>= 1) var += __shfl_xor(var, off);
    float rstd = rsqrtf(var * (1.0f / 512.0f) + 1e-5f);
    const float4* g4 = (const float4*)g;
    const float4* b4 = (const float4*)b;
    ushort_t* orow = out + (size_t)row * DIMX;
    float4 gg = g4[lane], bb = b4[lane];
    ushort4 o;
    o.x = f2bf((v0.x - mu) * rstd * gg.x + bb.x);
    o.y = f2bf((v0.y - mu) * rstd * gg.y + bb.y);
    o.z = f2bf((v0.z - mu) * rstd * gg.z + bb.z);
    o.w = f2bf((v0.w - mu) * rstd * gg.w + bb.w);
    *(ushort4*)(orow + lane * 4) = o;
    gg = g4[lane + 64]; bb = b4[lane + 64];
    o.x = f2bf((v1.x - mu) * rstd * gg.x + bb.x);
    o.y = f2bf((v1.y - mu) * rstd * gg.y + bb.y);
    o.z = f2bf((v1.z - mu) * rstd * gg.z + bb.z);
    o.w = f2bf((v1.w - mu) * rstd * gg.w + bb.w);
    *(ushort4*)(orow + 256 + lane * 4) = o;
}

// ---------------- weight transpose-convert: W[K,N] fp32 -> Wt[N,K] bf16 ----------------
__global__ __launch_bounds__(256) void wconv_kernel(const float* __restrict__ W,
                                                    ushort_t* __restrict__ Wt,
                                                    int K, int N) {
    __shared__ float tile[32][33];
    int bx = blockIdx.x * 32;  // n
    int by = blockIdx.y * 32;  // k
    int tx = threadIdx.x & 31, ty = threadIdx.x >> 5;
#pragma unroll
    for (int r = 0; r < 4; r++)
        tile[ty + r * 8][tx] = W[(size_t)(by + ty + r * 8) * N + bx + tx];
    __syncthreads();
#pragma unroll
    for (int r = 0; r < 4; r++)
        Wt[(size_t)(bx + ty + r * 8) * K + by + tx] = f2bf(tile[tx][ty + r * 8]);
}

// async global->LDS 16B per lane
__device__ __forceinline__ void gl_lds16(const void* g, void* l) {
    __builtin_amdgcn_global_load_lds(
        (const __attribute__((address_space(1))) unsigned int*)g,
        (__attribute__((address_space(3))) unsigned int*)l, 16, 0, 0);
}

// ---------------- bf16 MFMA GEMM: 128x128 tile, 16x16x32 ----------------
// A[M,K] bf16 row-major; Bt[N,K] bf16 row-major.
// EPI 0: C = A@B. EPI 1: C += A@B + bias. EPI 2: Cb = bf16(gelu(A@B+bias)). EPI 3: Cb = bf16(A@B).
template <int EPI>
__global__ __launch_bounds__(256) void gemm_mfma(const ushort_t* __restrict__ A,
                                                 const ushort_t* __restrict__ Bt,
                                                 const float* __restrict__ bias,
                                                 float* __restrict__ C,
                                                 ushort_t* __restrict__ Cb,
                                                 int M, int N, int K) {
    __shared__ ushort_t As[128 * 32];
    __shared__ ushort_t Bs[128 * 32];
    int t = threadIdx.x;
    int wave = t >> 6, lane = t & 63;
    int wm = wave >> 1, wn = wave & 1;
    int m0 = blockIdx.x * 128, n0 = blockIdx.y * 128;
    int q = lane >> 4, ml = lane & 15;

    floatx4 acc[4][4];
#pragma unroll
    for (int i = 0; i < 4; i++)
#pragma unroll
        for (int j = 0; j < 4; j++) acc[i][j] = (floatx4)(0.f);

    int srow = (lane >> 2);
    int scol = (lane & 3) * 8;
    const ushort_t* Ag = A + (size_t)(m0 + wave * 32 + srow) * K + scol;
    const ushort_t* Bg = Bt + (size_t)(n0 + wave * 32 + srow) * K + scol;
    ushort_t* AsW = &As[(wave * 32) * 32];
    ushort_t* BsW = &Bs[(wave * 32) * 32];

    for (int k0 = 0; k0 < K; k0 += 32) {
        gl_lds16(Ag + k0, AsW);
        gl_lds16(Ag + k0 + (size_t)16 * K, AsW + 16 * 32);
        gl_lds16(Bg + k0, BsW);
        gl_lds16(Bg + k0 + (size_t)16 * K, BsW + 16 * 32);
        __syncthreads();
        short8 a[4], b[4];
#pragma unroll
        for (int i = 0; i < 4; i++)
            a[i] = *(const short8*)&As[(wm * 64 + i * 16 + ml) * 32 + q * 8];
#pragma unroll
        for (int j = 0; j < 4; j++)
            b[j] = *(const short8*)&Bs[(wn * 64 + j * 16 + ml) * 32 + q * 8];
#pragma unroll
        for (int i = 0; i < 4; i++)
#pragma unroll
            for (int j = 0; j < 4; j++)
                acc[i][j] = __builtin_amdgcn_mfma_f32_16x16x32_bf16(a[i], b[j], acc[i][j], 0, 0, 0);
        __syncthreads();
    }

#pragma unroll
    for (int i = 0; i < 4; i++) {
#pragma unroll
        for (int r = 0; r < 4; r++) {
            size_t row = (size_t)m0 + wm * 64 + i * 16 + q * 4 + r;
#pragma unroll
            for (int j = 0; j < 4; j++) {
                int col = n0 + wn * 64 + j * 16 + ml;
                float v = acc[i][j][r];
                if (EPI == 0) {
                    C[row * N + col] = v;
                } else if (EPI == 1) {
                    C[row * N + col] += v + bias[col];
                } else if (EPI == 2) {
                    Cb[row * N + col] = f2bf(gelu_f(v + bias[col]));
                } else {
                    Cb[row * N + col] = f2bf(v);
                }
            }
        }
    }
}

// ---------------- fp32 VALU GEMM (final fc, N=32) ----------------
template <int DOACC, int DOGELU>
__global__ __launch_bounds__(256) void gemm_kernel(const float* __restrict__ A,
                                                   const float* __restrict__ B,
                                                   const float* __restrict__ bias,
                                                   float* __restrict__ C,
                                                   int M, int N, int K) {
    __shared__ float As[16][132];
    __shared__ float Bs[16][132];
    int t = threadIdx.x;
    int tx = t & 15, ty = t >> 4;
    int m0 = blockIdx.x * 128;
    int n0 = blockIdx.y * 128;
    float c[8][8];
#pragma unroll
    for (int i = 0; i < 8; i++)
#pragma unroll
        for (int j = 0; j < 8; j++) c[i][j] = 0.f;
    int am = t >> 1;
    int ak = (t & 1) * 8;
    const float* Aptr = A + (size_t)(m0 + am) * K + ak;
    int bn = (t & 15) * 8;
    int bk = t >> 4;
    bool bvalid = (n0 + bn) < N;
    const float* Bptr = B + (size_t)bk * N + n0 + bn;
    for (int k0 = 0; k0 < K; k0 += 16) {
        float4 a0 = *(const float4*)(Aptr + k0);
        float4 a1 = *(const float4*)(Aptr + k0 + 4);
        As[ak + 0][am] = a0.x; As[ak + 1][am] = a0.y;
        As[ak + 2][am] = a0.z; As[ak + 3][am] = a0.w;
        As[ak + 4][am] = a1.x; As[ak + 5][am] = a1.y;
        As[ak + 6][am] = a1.z; As[ak + 7][am] = a1.w;
        float4 b0 = make_float4(0.f, 0.f, 0.f, 0.f);
        float4 b1v = make_float4(0.f, 0.f, 0.f, 0.f);
        if (bvalid) {
            const float* bp = Bptr + (size_t)k0 * N;
            b0 = *(const float4*)bp;
            b1v = *(const float4*)(bp + 4);
        }
        *(float4*)&Bs[bk][bn] = b0;
        *(float4*)&Bs[bk][bn + 4] = b1v;
        __syncthreads();
#pragma unroll
        for (int kk = 0; kk < 16; kk++) {
            float4 av0 = *(const float4*)&As[kk][ty * 4];
            float4 av1 = *(const float4*)&As[kk][64 + ty * 4];
            float4 bv0 = *(const float4*)&Bs[kk][tx * 4];
            float4 bv1 = *(const float4*)&Bs[kk][64 + tx * 4];
            float a_[8] = {av0.x, av0.y, av0.z, av0.w, av1.x, av1.y, av1.z, av1.w};
            float b_[8] = {bv0.x, bv0.y, bv0.z, bv0.w, bv1.x, bv1.y, bv1.z, bv1.w};
#pragma unroll
            for (int i = 0; i < 8; i++)
#pragma unroll
                for (int j = 0; j < 8; j++) c[i][j] += a_[i] * b_[j];
        }
        __syncthreads();
    }
#pragma unroll
    for (int ih = 0; ih < 2; ih++)
#pragma unroll
        for (int il = 0; il < 4; il++) {
            size_t row = (size_t)m0 + ih * 64 + ty * 4 + il;
#pragma unroll
            for (int jh = 0; jh < 2; jh++) {
                int colbase = n0 + jh * 64 + tx * 4;
                if (colbase < N) {
                    float* cp = C + row * N + colbase;
#pragma unroll
                    for (int jl = 0; jl < 4; jl++) {
                        float v = c[ih * 4 + il][jh * 4 + jl];
                        if (bias) v += bias[colbase + jl];
                        if (DOGELU) v = gelu_f(v);
                        if (DOACC) v += cp[jl];
                        cp[jl] = v;
                    }
                }
            }
        }
}

// ---------------- global max over key features (bf16 K, no barriers in loop) ----------------
// rows are (token,head) pairs flattened: row r -> ushort offset r*64
__global__ __launch_bounds__(320) void kmax_kernel(const ushort_t* __restrict__ Kf,
                                                   const float* __restrict__ proj,
                                                   unsigned int* __restrict__ kmaxkey,
                                                   int rows_per_block) {
    int tid = threadIdx.x;
    float4 pr[16];
    if (tid < NB) {
#pragma unroll
        for (int j = 0; j < 16; j++) pr[j] = ((const float4*)proj)[tid * 16 + j];
    }
    float lmax = -3.0e38f;
    size_t r0 = (size_t)blockIdx.x * rows_per_block;
    if (tid < NB) {
#pragma unroll 4
        for (int r = 0; r < rows_per_block; r++) {
            float acc = dot64bf(Kf + (r0 + r) * DHE, pr);
            lmax = fmaxf(lmax, acc);
        }
    }
    lmax *= DN_F;
#pragma unroll
    for (int off = 32; off; off >>= 1) lmax = fmaxf(lmax, __shfl_xor(lmax, off));
    __shared__ float wmax[5];
    if ((tid & 63) == 0) wmax[tid >> 6] = lmax;
    __syncthreads();
    if (tid == 0) {
        float bm = wmax[0];
        for (int w = 1; w < 5; w++) bm = fmaxf(bm, wmax[w]);
        atomicMax(kmaxkey, fkey(bm));
    }
}

// ------------- ctx: kp_pre + e2-scaled V accumulation, 4-token groups -------------
// Accumulates (per b,h): CTX_raw[m][d] = sum_t expk_pre * e2k * v;
// KS_raw[m] = sum_t expk_pre * e2k; VS[d] = sum_t v (unscaled).
__global__ __launch_bounds__(320) void ctx_kernel(const ushort_t* __restrict__ Kf,
                                                  const ushort_t* __restrict__ Vf,
                                                  const float* __restrict__ proj,
                                                  const unsigned int* __restrict__ kmaxkey,
                                                  float* __restrict__ CTX,
                                                  float* __restrict__ KS,
                                                  float* __restrict__ VS,
                                                  int base_b) {
    __shared__ __align__(16) float kpsS[NB * 4];
    __shared__ __align__(16) float vS[DHE * 4];
    __shared__ __align__(16) float e2S[4];
    int tid = threadIdx.x;
    int h = blockIdx.x / HCH, ch = blockIdx.x % HCH;
    int bh = (base_b + (ch >> 5)) * NHEADS + h;
    int w = tid >> 6, d = tid & 63;
    float4 pr[16];
    if (tid < NB) {
#pragma unroll
        for (int j = 0; j < 16; j++) pr[j] = ((const float4*)proj)[tid * 16 + j];
    }
    float mx = funkey(*kmaxkey);
    float cacc[54];
#pragma unroll
    for (int k = 0; k < 54; k++) cacc[k] = 0.f;
    float ksum_r = 0.f, vsum_r = 0.f;
    int tokbase = ch * 256;
    for (int g = 0; g < 64; g++) {
        int tok = tokbase + g * 4;
        float kp[4] = {0.f, 0.f, 0.f, 0.f};
        if (tid < NB) {
#pragma unroll
            for (int t = 0; t < 4; t++) {
                float acc = dot64bf(Kf + (size_t)(tok + t) * DIMX + h * DHE, pr);
                kp[t] = __expf(acc * DN_F - mx);
            }
            *(float4*)&kpsS[tid * 4] = make_float4(kp[0], kp[1], kp[2], kp[3]);
        }
        if (w == 4) {
            float kv[4], vv[4], ss[4];
#pragma unroll
            for (int t = 0; t < 4; t++) {
                kv[t] = bfu(Kf[(size_t)(tok + t) * DIMX + h * DHE + d]);
                vv[t] = bfu(Vf[(size_t)(tok + t) * DIMX + h * DHE + d]);
                ss[t] = kv[t] * kv[t];
            }
#pragma unroll
            for (int off = 32; off; off >>= 1) {
#pragma unroll
                for (int t = 0; t < 4; t++) ss[t] += __shfl_xor(ss[t], off);
            }
            float e2[4];
#pragma unroll
            for (int t = 0; t < 4; t++) e2[t] = __expf(-ss[t] * 0.0625f);
            if (d < 4) e2S[d] = e2[d];
            *(float4*)&vS[d * 4] =
                make_float4(vv[0] * e2[0], vv[1] * e2[1], vv[2] * e2[2], vv[3] * e2[3]);
            vsum_r += vv[0] + vv[1] + vv[2] + vv[3];
        }
        __syncthreads();
        if (tid < NB) {
            float4 e24 = *(const float4*)e2S;
            ksum_r += kp[0] * e24.x + kp[1] * e24.y + kp[2] * e24.z + kp[3] * e24.w;
        }
        float4 vv4 = *(const float4*)&vS[d * 4];
#pragma unroll
        for (int k = 0; k < 54; k++) {
            int m = w + 5 * k;
            if (m < NB) {
                float4 kp4 = *(const float4*)&kpsS[m * 4];
                cacc[k] += kp4.x * vv4.x + kp4.y * vv4.y + kp4.z * vv4.z + kp4.w * vv4.w;
            }
        }
        __syncthreads();
    }
    float* ctxp = CTX + (size_t)bh * (NB * DHE);
#pragma unroll
    for (int k = 0; k < 54; k++) {
        int m = w + 5 * k;
        if (m < NB) atomicAdd(&ctxp[m * DHE + d], cacc[k]);
    }
    if (tid < NB) atomicAdd(&KS[(size_t)bh * NB + tid], ksum_r);
    if (w == 4) atomicAdd(&VS[(size_t)bh * DHE + d], vsum_r);
}

// ------------- o: qp_pre + exact-eps output, 4-token groups -------------
// o[d] = (e2q*sum_m expq*creg + EPS*sum_m creg) / (e2q*sum_m expq*ksr + EPS*sum_m ksr)
// creg = CTX_raw + EPS*VS[d]; ksr = KS_raw + EPS*8192  (RATIO cancels in the ratio)
__global__ __launch_bounds__(320) void o_kernel(const ushort_t* __restrict__ Qf,
                                                const float* __restrict__ proj,
                                                const float* __restrict__ CTX,
                                                const float* __restrict__ KS,
                                                const float* __restrict__ VS,
                                                ushort_t* __restrict__ Of,
                                                int base_b) {
    __shared__ __align__(16) float qpsS[NB * 4];
    __shared__ __align__(16) float redS[5 * 4];
    __shared__ __align__(16) float red2S[5 * 4];
    __shared__ __align__(16) float e2S[2][4];
    __shared__ __align__(16) float opartS[5 * DHE * 4];
    __shared__ float ctS[DHE];
    int tid = threadIdx.x;
    int h = blockIdx.x / HCH, ch = blockIdx.x % HCH;
    int bh = (base_b + (ch >> 5)) * NHEADS + h;
    int w = tid >> 6, d = tid & 63;
    float4 pr[16];
    if (tid < NB) {
#pragma unroll
        for (int j = 0; j < 16; j++) pr[j] = ((const float4*)proj)[tid * 16 + j];
    }
    float vs_eps = EPS_F * VS[(size_t)bh * DHE + d];
    const float* ctxp = CTX + (size_t)bh * (NB * DHE);
    float creg[54];
    float csum = 0.f;
#pragma unroll
    for (int k = 0; k < 54; k++) {
        int m = w + 5 * k;
        creg[k] = (m < NB) ? (ctxp[m * DHE + d] + vs_eps) : 0.f;
        csum += creg[k];
    }
    float ksr = (tid < NB) ? (KS[(size_t)bh * NB + tid] + EPS_F * 8192.0f) : 0.f;
    // one-time block reductions: kstot, ctS[d]
    float kst = ksr;
#pragma unroll
    for (int off = 32; off; off >>= 1) kst += __shfl_xor(kst, off);
    if ((tid & 63) == 0) redS[w] = kst;
    opartS[w * 256 + d * 4] = csum;
    __syncthreads();
    float kstot = redS[0] + redS[1] + redS[2] + redS[3] + redS[4];
    if (tid < DHE)
        ctS[tid] = opartS[tid * 4] + opartS[256 + tid * 4] + opartS[512 + tid * 4] +
                   opartS[768 + tid * 4] + opartS[1024 + tid * 4];
    __syncthreads();
    int tokbase = ch * 256;
    for (int g = 0; g < 64; g++) {
        int tok = tokbase + g * 4;
        int pb = g & 1;
        float xq[4] = {-3.0e38f, -3.0e38f, -3.0e38f, -3.0e38f};
        if (tid < NB) {
#pragma unroll
            for (int t = 0; t < 4; t++)
                xq[t] = dot64bf(Qf + (size_t)(tok + t) * DIMX + h * DHE, pr) * DN_F;
        }
        if (w == 4) {
            float qv[4], ss[4];
#pragma unroll
            for (int t = 0; t < 4; t++) {
                qv[t] = bfu(Qf[(size_t)(tok + t) * DIMX + h * DHE + d]);
                ss[t] = qv[t] * qv[t];
            }
#pragma unroll
            for (int off = 32; off; off >>= 1) {
#pragma unroll
                for (int t = 0; t < 4; t++) ss[t] += __shfl_xor(ss[t], off);
            }
            if (d < 4) e2S[pb][d] = __expf(-ss[d] * 0.0625f);
        }
        float m4[4] = {xq[0], xq[1], xq[2], xq[3]};
#pragma unroll
        for (int off = 32; off; off >>= 1) {
#pragma unroll
            for (int t = 0; t < 4; t++) m4[t] = fmaxf(m4[t], __shfl_xor(m4[t], off));
        }
        if ((tid & 63) == 0) *(float4*)&redS[w * 4] = make_float4(m4[0], m4[1], m4[2], m4[3]);
        __syncthreads();  // b1: maxes + e2S ready
        float rmax[4], dp[4] = {0.f, 0.f, 0.f, 0.f};
#pragma unroll
        for (int t = 0; t < 4; t++)
            rmax[t] = fmaxf(fmaxf(fmaxf(redS[t], redS[4 + t]), fmaxf(redS[8 + t], redS[12 + t])),
                            redS[16 + t]);
        if (tid < NB) {
            float qp[4];
#pragma unroll
            for (int t = 0; t < 4; t++) {
                qp[t] = __expf(xq[t] - rmax[t]);
                dp[t] = qp[t] * ksr;
            }
            *(float4*)&qpsS[tid * 4] = make_float4(qp[0], qp[1], qp[2], qp[3]);
        }
#pragma unroll
        for (int off = 32; off; off >>= 1) {
#pragma unroll
            for (int t = 0; t < 4; t++) dp[t] += __shfl_xor(dp[t], off);
        }
        if ((tid & 63) == 0) *(float4*)&red2S[w * 4] = make_float4(dp[0], dp[1], dp[2], dp[3]);
        __syncthreads();  // b2: qps + denom partials ready
        float at[4] = {0.f, 0.f, 0.f, 0.f};
#pragma unroll
        for (int k = 0; k < 54; k++) {
            int m = w + 5 * k;
            if (m < NB) {
                float4 q4 = *(const float4*)&qpsS[m * 4];
                at[0] += q4.x * creg[k]; at[1] += q4.y * creg[k];
                at[2] += q4.z * creg[k]; at[3] += q4.w * creg[k];
            }
        }
        *(float4*)&opartS[w * 256 + d * 4] = make_float4(at[0], at[1], at[2], at[3]);
        __syncthreads();  // b3: opart ready
        if (tid < 256) {
            int t = tid >> 6, dd = tid & 63;
            float s = opartS[dd * 4 + t] + opartS[256 + dd * 4 + t] + opartS[512 + dd * 4 + t] +
                      opartS[768 + dd * 4 + t] + opartS[1024 + dd * 4 + t];
            float B = red2S[t] + red2S[4 + t] + red2S[8 + t] + red2S[12 + t] + red2S[16 + t];
            float e2q = e2S[pb][t];
            float num = e2q * s + EPS_F * ctS[dd];
            float den = e2q * B + EPS_F * kstot;
            Of[(size_t)(tok + t) * DIMX + h * DHE + dd] = f2bf(num / den);
        }
    }
}

extern "C" void kernel_launch(void* const* d_in, const int* in_sizes, int n_in,
                              void* d_out, int out_size, void* d_ws, size_t ws_size,
                              hipStream_t stream) {
    (void)in_sizes; (void)n_in; (void)out_size; (void)ws_size;
    const float* src  = (const float*)d_in[0];
    const float* proj = (const float*)d_in[1];
    const float* ln1g = (const float*)d_in[2];
    const float* ln1b = (const float*)d_in[3];
    const float* Wq   = (const float*)d_in[4];
    const float* Wk   = (const float*)d_in[5];
    const float* Wv   = (const float*)d_in[6];
    const float* Wo   = (const float*)d_in[7];
    const float* bo   = (const float*)d_in[8];
    const float* ln2g = (const float*)d_in[9];
    const float* ln2b = (const float*)d_in[10];
    const float* W1   = (const float*)d_in[11];
    const float* b1   = (const float*)d_in[12];
    const float* W2   = (const float*)d_in[13];
    const float* b2   = (const float*)d_in[14];
    const float* fcw  = (const float*)d_in[15];
    const float* fcb  = (const float*)d_in[16];
    float* out = (float*)d_out;

    // Workspace (~136 MiB, proven-safe range)
    const size_t TD = (size_t)NTOK * DIMX;   // 16.77M elems
    const size_t HD = (size_t)HALF * DIMX;   //  8.39M elems
    const size_t SD = (size_t)SEQ * DIMX;    //  4.19M elems
    float* X      = (float*)d_ws;                       // fp32 residual, full batch (64 MiB)
    ushort_t* H   = (ushort_t*)(X + TD);                // bf16 LN out, full batch (32 MiB)
    ushort_t* Pb  = H + TD;                             // bf16 K/Q per half (16 MiB)
    ushort_t* Rb  = Pb + HD;                            // bf16 V/o per half (16 MiB); Pb..Rb = FF hidden
    float* CTXb   = (float*)(Rb + HD);                  // 32*266*64
    float* KSb    = CTXb + 32 * NB * DHE;               // 32*266
    float* VSb    = KSb + 32 * NB;                      // 32*64
    unsigned int* KMAX = (unsigned int*)(VSb + 32 * DHE);
    ushort_t* Wqt = (ushort_t*)(KMAX + 4);
    ushort_t* Wkt = Wqt + DIMX * DIMX;
    ushort_t* Wvt = Wkt + DIMX * DIMX;
    ushort_t* Wot = Wvt + DIMX * DIMX;
    ushort_t* W1t = Wot + DIMX * DIMX;                  // [FFD, DIMX]
    ushort_t* W2t = W1t + (size_t)DIMX * FFD;           // [DIMX, FFD]
    const int NZ = 32 * NB * DHE + 32 * NB + 32 * DHE + 4;

    hipMemcpyAsync(X, src, sizeof(float) * TD, hipMemcpyDeviceToDevice, stream);

    dim3 gH(HALF / 128, DIMX / 128);   // (128,4) half-batch proj GEMM
    dim3 gF1(SEQ / 128, FFD / 128);    // (64,16)
    dim3 gF2(SEQ / 128, DIMX / 128);   // (64,4)
    for (int L = 0; L < NLAYER; L++) {
        const float* pj = proj + (size_t)L * NB * DHE;
        wconv_kernel<<<dim3(16, 16), 256, 0, stream>>>(Wq + (size_t)L * DIMX * DIMX, Wqt, DIMX, DIMX);
        wconv_kernel<<<dim3(16, 16), 256, 0, stream>>>(Wk + (size_t)L * DIMX * DIMX, Wkt, DIMX, DIMX);
        wconv_kernel<<<dim3(16, 16), 256, 0, stream>>>(Wv + (size_t)L * DIMX * DIMX, Wvt, DIMX, DIMX);
        wconv_kernel<<<dim3(16, 16), 256, 0, stream>>>(Wo + (size_t)L * DIMX * DIMX, Wot, DIMX, DIMX);
        wconv_kernel<<<dim3(64, 16), 256, 0, stream>>>(W1 + (size_t)L * DIMX * FFD, W1t, DIMX, FFD);
        wconv_kernel<<<dim3(16, 64), 256, 0, stream>>>(W2 + (size_t)L * FFD * DIMX, W2t, FFD, DIMX);
        zero_kernel<<<(NZ + 255) / 256, 256, 0, stream>>>(CTXb, NZ);
        ln_bf16_kernel<<<NTOK / 4, 256, 0, stream>>>(X, ln1g + L * DIMX, ln1b + L * DIMX, H);
        // pass 1: global key-feature max (K recomputed later; Pb reused)
        for (int half = 0; half < 2; half++) {
            gemm_mfma<3><<<gH, 256, 0, stream>>>(H + half * HD, Wkt, nullptr, nullptr, Pb, HALF, DIMX, DIMX);
            kmax_kernel<<<512, 320, 0, stream>>>(Pb, pj, KMAX, (HALF * NHEADS) / 512);
        }
        // pass 2: attention per half
        for (int half = 0; half < 2; half++) {
            const ushort_t* Hh = H + half * HD;
            gemm_mfma<3><<<gH, 256, 0, stream>>>(Hh, Wkt, nullptr, nullptr, Pb, HALF, DIMX, DIMX);
            gemm_mfma<3><<<gH, 256, 0, stream>>>(Hh, Wvt, nullptr, nullptr, Rb, HALF, DIMX, DIMX);
            ctx_kernel<<<NHEADS * HCH, 320, 0, stream>>>(Pb, Rb, pj, KMAX, CTXb, KSb, VSb, half * 2);
            gemm_mfma<3><<<gH, 256, 0, stream>>>(Hh, Wqt, nullptr, nullptr, Pb, HALF, DIMX, DIMX);
            o_kernel<<<NHEADS * HCH, 320, 0, stream>>>(Pb, pj, CTXb, KSb, VSb, Rb, half * 2);
            gemm_mfma<1><<<gH, 256, 0, stream>>>(Rb, Wot, bo + L * DIMX, X + half * HD, nullptr, HALF, DIMX, DIMX);
        }
        // FF
        ln_bf16_kernel<<<NTOK / 4, 256, 0, stream>>>(X, ln2g + L * DIMX, ln2b + L * DIMX, H);
        for (int b = 0; b < BATCH; b++) {
            gemm_mfma<2><<<gF1, 256, 0, stream>>>(H + (size_t)b * SD, W1t, b1 + L * FFD, nullptr, Pb, SEQ, FFD, DIMX);
            gemm_mfma<1><<<gF2, 256, 0, stream>>>(Pb, W2t, b2 + L * DIMX, X + (size_t)b * SD, nullptr, SEQ, DIMX, FFD);
        }
    }
    gemm_kernel<0, 0><<<dim3(NTOK / 128, 1), 256, 0, stream>>>(X, fcw, fcb, out, NTOK, OUTD, DIMX);
}